// Round 1
// 1684.383 us; speedup vs baseline: 1.3077x; 1.3077x over previous
//
#include <hip/hip_runtime.h>
#include <cstdint>
#include <cstddef>

// Problem constants
#define B_     256
#define S_     196
#define DV_    2048
#define DA_    620
#define DATT_  1200
#define DATTP_ 1280   // DATT padded to 10 * BN
#define DOUT_  1024

#define IVB_SSTR 224  // per-b row padding for bf16 transposed input (>= 112+112)

typedef unsigned short ushort_t;
typedef __attribute__((ext_vector_type(8))) short short8;
typedef __attribute__((ext_vector_type(4))) float floatx4;

__device__ __forceinline__ float bf2f(unsigned int u) {
    union { unsigned int i; float f; } v; v.i = u << 16; return v.f;
}
__device__ __forceinline__ ushort_t f2bf(float x) {   // RNE f32->bf16
    union { float f; unsigned int u; } c; c.f = x;
    unsigned int r = (c.u + 0x7fffu + ((c.u >> 16) & 1u)) >> 16;
    return (ushort_t)r;
}

struct F4 { float v[4]; };
struct F8 { float v[8]; };

// Generic input loaders: f=1 -> fp32 buffer, f=0 -> bf16 buffer. i = element idx.
__device__ __forceinline__ F4 ld4(const void* p, size_t i, int f) {
    F4 r;
    if (f) {
        float4 u = *(const float4*)((const float*)p + i);
        r.v[0]=u.x; r.v[1]=u.y; r.v[2]=u.z; r.v[3]=u.w;
    } else {
        uint2 u = *(const uint2*)((const ushort_t*)p + i);
        r.v[0]=bf2f(u.x & 0xffffu); r.v[1]=bf2f(u.x >> 16);
        r.v[2]=bf2f(u.y & 0xffffu); r.v[3]=bf2f(u.y >> 16);
    }
    return r;
}
__device__ __forceinline__ F8 ld8(const void* p, size_t i, int f) {
    F8 r;
    if (f) {
        float4 a = *(const float4*)((const float*)p + i);
        float4 b = *(const float4*)((const float*)p + i + 4);
        r.v[0]=a.x; r.v[1]=a.y; r.v[2]=a.z; r.v[3]=a.w;
        r.v[4]=b.x; r.v[5]=b.y; r.v[6]=b.z; r.v[7]=b.w;
    } else {
        uint4 u = *(const uint4*)((const ushort_t*)p + i);
        r.v[0]=bf2f(u.x & 0xffffu); r.v[1]=bf2f(u.x >> 16);
        r.v[2]=bf2f(u.y & 0xffffu); r.v[3]=bf2f(u.y >> 16);
        r.v[4]=bf2f(u.z & 0xffffu); r.v[5]=bf2f(u.z >> 16);
        r.v[6]=bf2f(u.w & 0xffffu); r.v[7]=bf2f(u.w >> 16);
    }
    return r;
}
__device__ __forceinline__ float lds1(const void* p, size_t i, int f) {
    return f ? ((const float*)p)[i] : bf2f((unsigned int)((const ushort_t*)p)[i]);
}
__device__ __forceinline__ void stout(void* p, size_t i, float v, int f) {
    if (f) ((float*)p)[i] = v; else ((ushort_t*)p)[i] = f2bf(v);
}

// async 16B global->LDS copy (wave-uniform LDS base + lane*16, per-lane src)
typedef const __attribute__((address_space(1))) unsigned int* gas_t;
typedef __attribute__((address_space(3))) unsigned int* las_t;
__device__ __forceinline__ void async_cp16(const ushort_t* src, ushort_t* lds) {
    __builtin_amdgcn_global_load_lds((gas_t)(const void*)src, (las_t)(void*)lds, 16, 0, 0);
}

// ---------------------------------------------------------------------------
// Kernel 0: dtype detector. emb ~ N(0,1). bf16 data: ~64/64 ushorts have sane
// bf16 exponents (100..140). fp32 data: only the 32 high halves do (~37/64).
// ---------------------------------------------------------------------------
__global__ __launch_bounds__(64) void k0_detect(const void* __restrict__ emb,
                                                int* __restrict__ flags)
{
    int lane = threadIdx.x;
    unsigned int u = ((const ushort_t*)emb)[lane];
    unsigned int e = (u >> 7) & 0xffu;
    bool sane = (e >= 100u && e <= 140u);
    unsigned long long m = __ballot(sane);
    if (lane == 0) flags[0] = (__popcll(m) >= 48) ? 0 : 1;   // 0=bf16, 1=fp32
}

// ---------------------------------------------------------------------------
// Kernel 1: x_a_vec gather + xa_w = relu(x_a_vec @ W_lin_a^T + b)*w_att (padded
// to 1280 with zeros) and a_feat = x_a_vec @ W_ans^T + b_ans -> out[:,1024:]
// ---------------------------------------------------------------------------
__global__ __launch_bounds__(256) void k1_xa(
    const void* __restrict__ emb, const int* __restrict__ ia,
    const void* __restrict__ Wla, const void* __restrict__ bla,
    const void* __restrict__ watt,
    const void* __restrict__ Wans, const void* __restrict__ bans,
    float* __restrict__ xa_w, void* __restrict__ out,
    const int* __restrict__ flags)
{
    const int f = flags[0];
    __shared__ float xa[16][DA_];
    int t = threadIdx.x;
    int bc = blockIdx.x & 15, rc = blockIdx.x >> 4;
    int b0 = bc * 16;
    for (int idx = t; idx < 16 * 155; idx += 256) {
        int row = idx / 155, c8 = idx % 155;
        int cls = ia[b0 + row];
        cls = min(max(cls, 0), 2999);
        F4 u = ld4(emb, (size_t)cls * DA_ + c8 * 4, f);
        xa[row][c8*4+0] = u.v[0]; xa[row][c8*4+1] = u.v[1];
        xa[row][c8*4+2] = u.v[2]; xa[row][c8*4+3] = u.v[3];
    }
    __syncthreads();
    int wave = t >> 6, lane = t & 63;
    for (int j = 0; j < 36; ++j) {
        int row = rc * 144 + wave + 4 * j;   // 0..2303
        bool is_xa = row < DATTP_;
        int n = row;
        int o = row - DATTP_;
        const void* wmat = is_xa ? Wla : Wans;
        size_t wrow = is_xa ? (size_t)n * DA_ : (size_t)o * DA_;
        bool live = !(is_xa && n >= DATT_);
        float wv[12];
        if (live) {
            #pragma unroll
            for (int i = 0; i < 3; ++i) {
                int c = 4 * lane + 256 * i;
                if (c < DA_) {
                    F4 u = ld4(wmat, wrow + c, f);
                    wv[i*4+0]=u.v[0]; wv[i*4+1]=u.v[1];
                    wv[i*4+2]=u.v[2]; wv[i*4+3]=u.v[3];
                } else { wv[i*4+0]=0.f; wv[i*4+1]=0.f; wv[i*4+2]=0.f; wv[i*4+3]=0.f; }
            }
        }
        for (int bb = 0; bb < 16; ++bb) {
            float p = 0.f;
            if (live) {
                #pragma unroll
                for (int i = 0; i < 3; ++i) {
                    int c = 4 * lane + 256 * i;
                    if (c < DA_) {
                        p += wv[i*4+0]*xa[bb][c+0] + wv[i*4+1]*xa[bb][c+1]
                           + wv[i*4+2]*xa[bb][c+2] + wv[i*4+3]*xa[bb][c+3];
                    }
                }
            }
            #pragma unroll
            for (int off = 1; off < 64; off <<= 1)
                p += __shfl_xor(p, off, 64);
            if (lane == 0) {
                int b = b0 + bb;
                if (is_xa) {
                    float v = 0.f;
                    if (n < DATT_)
                        v = fmaxf(p + lds1(bla, n, f), 0.f) * lds1(watt, n, f);
                    xa_w[(size_t)b * DATTP_ + n] = v;
                } else {
                    stout(out, (size_t)b * 2048 + 1024 + o,
                          p + lds1(bans, o, f), f);
                }
            }
        }
    }
}

// ---------------------------------------------------------------------------
// Prepass W: Wcb[n][c] = bf16(W_conv_v[n][c]), rows 1200..1279 zeroed.
// ---------------------------------------------------------------------------
__global__ __launch_bounds__(256) void kp_w(
    const void* __restrict__ Wc, ushort_t* __restrict__ Wcb,
    const int* __restrict__ flags)
{
    const int f = flags[0];
    int n = blockIdx.x;                 // 0..1279
    int t = threadIdx.x;
    size_t o = (size_t)n * DV_ + t * 8;
    uint4 w = make_uint4(0u, 0u, 0u, 0u);
    if (n < DATT_) {
        F8 u = ld8(Wc, o, f);
        w.x = (unsigned)f2bf(u.v[0]) | ((unsigned)f2bf(u.v[1]) << 16);
        w.y = (unsigned)f2bf(u.v[2]) | ((unsigned)f2bf(u.v[3]) << 16);
        w.z = (unsigned)f2bf(u.v[4]) | ((unsigned)f2bf(u.v[5]) << 16);
        w.w = (unsigned)f2bf(u.v[6]) | ((unsigned)f2bf(u.v[7]) << 16);
    }
    *(uint4*)&Wcb[o] = w;
}

// ---------------------------------------------------------------------------
// Prepass iv: ivb[b][s][c] = bf16(input_v[b][c][s]).  64c x 64s LDS tiles,
// 16B-unit XOR swizzle (unit ^= c>>2) -> both LDS sides conflict-free (2-way),
// both global sides coalesced. Rows s in [196,224) left unwritten (garbage ok:
// GEMM output rows for s>=196 are never stored).
// grid = 256 b * 32 cchunk * 4 schunk
// ---------------------------------------------------------------------------
__global__ __launch_bounds__(256) void kp_iv(
    const void* __restrict__ iv, ushort_t* __restrict__ ivb,
    const int* __restrict__ flags)
{
    const int f = flags[0];
    __shared__ float tile[64 * 64];
    int t = threadIdx.x;
    int bid = blockIdx.x;
    int b  = bid >> 7;
    int cc = (bid >> 2) & 31;
    int sc = bid & 3;
    int c0 = cc * 64, s0 = sc * 64;
    #pragma unroll
    for (int i = 0; i < 4; ++i) {
        int idx = t + 256 * i;
        int c = idx >> 4, q = idx & 15;
        int s = s0 + 4 * q;
        float4 v = make_float4(0.f, 0.f, 0.f, 0.f);
        if (s < S_) {   // s=192 -> exactly one full float4; s>=196 skipped
            F4 u = ld4(iv, ((size_t)b * DV_ + (c0 + c)) * (size_t)S_ + s, f);
            v = make_float4(u.v[0], u.v[1], u.v[2], u.v[3]);
        }
        int up = q ^ (c >> 2);
        *(float4*)&tile[c * 64 + up * 4] = v;
    }
    __syncthreads();
    #pragma unroll
    for (int i = 0; i < 4; ++i) {
        int sl = (t >> 4) + 16 * i;          // local s row 0..63
        int s = s0 + sl;
        int g = t & 15;                      // 4 c's per thread
        if (s < S_) {
            int uw = ((sl >> 2) ^ g) << 2;
            ushort4 w;
            w.x = f2bf(tile[(4*g + 0) * 64 + uw + (sl & 3)]);
            w.y = f2bf(tile[(4*g + 1) * 64 + uw + (sl & 3)]);
            w.z = f2bf(tile[(4*g + 2) * 64 + uw + (sl & 3)]);
            w.w = f2bf(tile[(4*g + 3) * 64 + uw + (sl & 3)]);
            *(ushort4*)&ivb[(size_t)b * (IVB_SSTR * DV_) + (size_t)s * DV_ + c0 + 4*g] = w;
        }
    }
}

// ---------------------------------------------------------------------------
// Kernel 2 v2: fused conv-GEMM + logits reduction on prepacked bf16 operands.
// A = ivb[b][s][c] (k-contiguous), B = Wcb[n][c] (k-contiguous).
// BM=112 (7 or 6 m-tiles), BN=128 (2 n-tiles/wave), BK=64.
// Staging: global_load_lds width=16, linear LDS dest, XOR-swizzled source;
// ds_read_b128 frag reads apply the same swizzle (unit ^= row&7) -> 2-way free.
// grid = 5120 (XCD-swizzled so the 20 blocks of each b share one XCD's L2).
// ---------------------------------------------------------------------------
#define BM2_ 112
#define BN2_ 128

template<int MT>
__device__ __forceinline__ void k2_body(
    const ushort_t* __restrict__ ivA,   // ivb + b*IVB_SSTR*2048 + s0*2048
    const ushort_t* __restrict__ Bp,    // Wcb + n0*2048
    const void* __restrict__ bcv, const float* __restrict__ xa_w,
    float* __restrict__ logits, int f,
    ushort_t* sA, ushort_t* sB, float* llog,
    int b, int s0, int n0, int rows_valid, int t)
{
    const int A_units = MT * 16 * 8;            // 16B units in A tile (mult of 64)
    const int total_units = A_units + BN2_ * 8;
    int wave = t >> 6, lane = t & 63;
    int lquad = lane >> 4, l15 = lane & 15;
    int nbase = wave * 32;                      // 2 n-tiles per wave

    floatx4 acc[MT][2];
    #pragma unroll
    for (int mt = 0; mt < MT; ++mt) {
        acc[mt][0] = floatx4{0.f, 0.f, 0.f, 0.f};
        acc[mt][1] = floatx4{0.f, 0.f, 0.f, 0.f};
    }

    for (int kt = 0; kt < DV_ / 64; ++kt) {
        const ushort_t* aK = ivA + kt * 64;
        const ushort_t* bK = Bp  + kt * 64;
        __syncthreads();
        for (int u = t; u < total_units; u += 256) {
            int ub = u & ~63;                   // wave-uniform LDS base unit
            if (u < A_units) {
                int r = u >> 3, up = u & 7, ul = up ^ (r & 7);
                async_cp16(aK + (size_t)r * DV_ + ul * 8, sA + ub * 8);
            } else {
                int v = u - A_units;
                int r = v >> 3, up = v & 7, ul = up ^ (r & 7);
                async_cp16(bK + (size_t)r * DV_ + ul * 8, sB + (ub - A_units) * 8);
            }
        }
        __syncthreads();
        #pragma unroll
        for (int ks = 0; ks < 2; ++ks) {
            int usw = (ks * 4 + lquad) ^ (l15 & 7);   // row&7 == l15&7 for all tiles
            short8 bf0 = *(const short8*)&sB[((nbase      + l15) * 8 + usw) * 8];
            short8 bf1 = *(const short8*)&sB[((nbase + 16 + l15) * 8 + usw) * 8];
            #pragma unroll
            for (int mt = 0; mt < MT; ++mt) {
                short8 af = *(const short8*)&sA[((mt * 16 + l15) * 8 + usw) * 8];
                acc[mt][0] = __builtin_amdgcn_mfma_f32_16x16x32_bf16(af, bf0, acc[mt][0], 0, 0, 0);
                acc[mt][1] = __builtin_amdgcn_mfma_f32_16x16x32_bf16(af, bf1, acc[mt][1], 0, 0, 0);
            }
        }
    }

    // Epilogue: relu(acc + bias) * xa_w, reduce over n.
    // C/D layout (16x16x32): col(n) = lane&15, row(s) = (lane>>4)*4 + reg.
    float bias[2], xw[2];
    #pragma unroll
    for (int bt = 0; bt < 2; ++bt) {
        int ng = n0 + nbase + bt * 16 + l15;
        bias[bt] = (ng < DATT_) ? lds1(bcv, ng, f) : 0.f;
        xw[bt]   = (ng < DATT_) ? xa_w[(size_t)b * DATTP_ + ng] : 0.f;
    }
    float plog[MT][4];
    #pragma unroll
    for (int mt = 0; mt < MT; ++mt)
        #pragma unroll
        for (int r = 0; r < 4; ++r) {
            float v0 = fmaxf(acc[mt][0][r] + bias[0], 0.f) * xw[0];
            float v1 = fmaxf(acc[mt][1][r] + bias[1], 0.f) * xw[1];
            plog[mt][r] = v0 + v1;
        }
    #pragma unroll
    for (int off = 1; off <= 8; off <<= 1)
        #pragma unroll
        for (int mt = 0; mt < MT; ++mt)
            #pragma unroll
            for (int r = 0; r < 4; ++r)
                plog[mt][r] += __shfl_xor(plog[mt][r], off, 64);
    if (l15 == 0) {
        #pragma unroll
        for (int mt = 0; mt < MT; ++mt)
            #pragma unroll
            for (int r = 0; r < 4; ++r)
                atomicAdd(&llog[mt * 16 + lquad * 4 + r], plog[mt][r]);
    }
    __syncthreads();
    if (t < rows_valid)
        atomicAdd(&logits[(size_t)b * 256 + s0 + t], llog[t]);
}

__global__ __launch_bounds__(256) void k2_gemm_v2(
    const ushort_t* __restrict__ ivb, const ushort_t* __restrict__ Wcb,
    const void* __restrict__ bcv, const float* __restrict__ xa_w,
    float* __restrict__ logits, const int* __restrict__ flags)
{
    const int f = flags[0];
    __shared__ ushort_t sA[BM2_ * 64];
    __shared__ ushort_t sB[BN2_ * 64];
    __shared__ float llog[BM2_];
    int t = threadIdx.x;
    int bid = blockIdx.x;
    // bijective XCD swizzle (5120 % 8 == 0): each XCD gets 640 consecutive
    // logical ids = 32 b's worth of blocks -> per-b A panel stays in that L2.
    int lg = (bid & 7) * 640 + (bid >> 3);
    int b = lg / 20, rem = lg % 20;
    int mb = rem / 10, nb = rem % 10;
    int s0 = mb * BM2_, n0 = nb * BN2_;
    int rows_valid = min(BM2_, S_ - s0);       // 112 or 84
    if (t < BM2_) llog[t] = 0.f;
    const ushort_t* ivA = ivb + (size_t)b * (IVB_SSTR * DV_) + (size_t)s0 * DV_;
    const ushort_t* Bp  = Wcb + (size_t)n0 * DV_;
    if (mb == 0)
        k2_body<7>(ivA, Bp, bcv, xa_w, logits, f, sA, sB, llog, b, s0, n0, rows_valid, t);
    else
        k2_body<6>(ivA, Bp, bcv, xa_w, logits, f, sA, sB, llog, b, s0, n0, rows_valid, t);
}

// ---------------------------------------------------------------------------
// Kernel 2 fallback (workspace too small): original fused conv-GEMM.
// ---------------------------------------------------------------------------
#define BM_  112
#define BN_  128
#define LDA_ 40
#define LDB_ 40

__global__ __launch_bounds__(256) void k2_gemm(
    const void* __restrict__ iv, const void* __restrict__ Wc,
    const void* __restrict__ bcv, const float* __restrict__ xa_w,
    float* __restrict__ logits, const int* __restrict__ flags)
{
    const int f = flags[0];
    __shared__ ushort_t Al[BM_ * LDA_];
    __shared__ ushort_t Bl[BN_ * LDB_];
    __shared__ float llog[BM_];

    int t = threadIdx.x;
    int bid = blockIdx.x;
    int b   = bid / 20;
    int rem = bid % 20;
    int mb = rem / 10, nb = rem % 10;
    int s0 = mb * BM_, n0 = nb * BN_;
    int rows_valid = min(BM_, S_ - s0);
    int cpc = (rows_valid + 7) >> 3;
    int totA = 32 * cpc;

    if (t < BM_) llog[t] = 0.f;
    for (int idx = t; idx < (BM_ - rows_valid) * LDA_; idx += 256)
        Al[rows_valid * LDA_ + idx] = 0;

    size_t ivbase = (size_t)b * DV_ * S_;

    int wave = t >> 6, lane = t & 63;
    int lquad = lane >> 4, l15 = lane & 15;
    int nbase = wave * 32;

    floatx4 acc[7][2];
    #pragma unroll
    for (int mt = 0; mt < 7; ++mt) {
        acc[mt][0] = floatx4{0.f, 0.f, 0.f, 0.f};
        acc[mt][1] = floatx4{0.f, 0.f, 0.f, 0.f};
    }

    for (int kt = 0; kt < DV_ / 32; ++kt) {
        int k0 = kt * 32;
        __syncthreads();
        for (int idx = t; idx < totA; idx += 256) {
            int c = idx & 31, j = idx >> 5;
            int sr = min(8 * j, rows_valid - 8);
            F8 u = ld8(iv, ivbase + (size_t)(k0 + c) * S_ + s0 + sr, f);
            #pragma unroll
            for (int i = 0; i < 8; ++i)
                Al[(sr + i) * LDA_ + c] = f2bf(u.v[i]);
        }
        for (int idx = t; idx < 512; idx += 256) {
            int nl = idx >> 2, kc = idx & 3;
            int ng = n0 + nl;
            if (ng < DATT_) {
                F8 u = ld8(Wc, (size_t)ng * DV_ + k0 + kc * 8, f);
                #pragma unroll
                for (int i = 0; i < 8; ++i)
                    Bl[nl * LDB_ + kc * 8 + i] = f2bf(u.v[i]);
            } else {
                #pragma unroll
                for (int i = 0; i < 8; ++i)
                    Bl[nl * LDB_ + kc * 8 + i] = 0;
            }
        }
        __syncthreads();
        short8 bf0 = *(const short8*)&Bl[(nbase + l15) * LDB_ + lquad * 8];
        short8 bf1 = *(const short8*)&Bl[(nbase + 16 + l15) * LDB_ + lquad * 8];
        #pragma unroll
        for (int mt = 0; mt < 7; ++mt) {
            short8 af = *(const short8*)&Al[(mt * 16 + l15) * LDA_ + lquad * 8];
            acc[mt][0] = __builtin_amdgcn_mfma_f32_16x16x32_bf16(af, bf0, acc[mt][0], 0, 0, 0);
            acc[mt][1] = __builtin_amdgcn_mfma_f32_16x16x32_bf16(af, bf1, acc[mt][1], 0, 0, 0);
        }
    }

    float bias[2], xw[2];
    #pragma unroll
    for (int bt = 0; bt < 2; ++bt) {
        int ng = n0 + nbase + bt * 16 + l15;
        bias[bt] = (ng < DATT_) ? lds1(bcv, ng, f) : 0.f;
        xw[bt]   = (ng < DATT_) ? xa_w[(size_t)b * DATTP_ + ng] : 0.f;
    }
    float plog[7][4];
    #pragma unroll
    for (int mt = 0; mt < 7; ++mt)
        #pragma unroll
        for (int r = 0; r < 4; ++r) {
            float v0 = fmaxf(acc[mt][0][r] + bias[0], 0.f) * xw[0];
            float v1 = fmaxf(acc[mt][1][r] + bias[1], 0.f) * xw[1];
            plog[mt][r] = v0 + v1;
        }
    #pragma unroll
    for (int off = 1; off <= 8; off <<= 1)
        #pragma unroll
        for (int mt = 0; mt < 7; ++mt)
            #pragma unroll
            for (int r = 0; r < 4; ++r)
                plog[mt][r] += __shfl_xor(plog[mt][r], off, 64);
    if (l15 == 0) {
        #pragma unroll
        for (int mt = 0; mt < 7; ++mt)
            #pragma unroll
            for (int r = 0; r < 4; ++r)
                atomicAdd(&llog[mt * 16 + lquad * 4 + r], plog[mt][r]);
    }
    __syncthreads();
    if (t < rows_valid)
        atomicAdd(&logits[(size_t)b * 256 + s0 + t], llog[t]);
}

// ---------------------------------------------------------------------------
// Kernel 3a: softmax over s (196) per b, IN PLACE.
// ---------------------------------------------------------------------------
__global__ __launch_bounds__(64) void k3a_softmax(float* __restrict__ logits)
{
    int b = blockIdx.x, lane = threadIdx.x;
    float v[4]; float mx = -1e30f;
    #pragma unroll
    for (int i = 0; i < 4; ++i) {
        int s = lane + 64 * i;
        v[i] = (s < S_) ? logits[(size_t)b * 256 + s] : -1e30f;
        union { float f; unsigned u; } cv; cv.f = v[i];
        if ((cv.u & 0x7f800000u) == 0x7f800000u) v[i] = -1e30f;
        mx = fmaxf(mx, v[i]);
    }
    #pragma unroll
    for (int off = 1; off < 64; off <<= 1)
        mx = fmaxf(mx, __shfl_xor(mx, off, 64));
    float e[4]; float sum = 0.f;
    #pragma unroll
    for (int i = 0; i < 4; ++i) {
        int s = lane + 64 * i;
        e[i] = (s < S_) ? __expf(v[i] - mx) : 0.f;
        sum += e[i];
    }
    #pragma unroll
    for (int off = 1; off < 64; off <<= 1)
        sum += __shfl_xor(sum, off, 64);
    float inv = 1.f / sum;
    #pragma unroll
    for (int i = 0; i < 4; ++i) {
        int s = lane + 64 * i;
        if (s < S_) logits[(size_t)b * 256 + s] = e[i] * inv;
    }
}

// ---------------------------------------------------------------------------
// Kernel 3b: x_v_att[b,d] = sum_s attn[b,s] * input_v[b,d,s]
// ---------------------------------------------------------------------------
__global__ __launch_bounds__(256) void k3b_wsum(
    const void* __restrict__ iv, const float* __restrict__ attn,
    float* __restrict__ xvatt, const int* __restrict__ flags)
{
    const int f = flags[0];
    __shared__ float at[200];
    int t = threadIdx.x;
    int b = blockIdx.x >> 3, dc = blockIdx.x & 7;
    if (t < S_) at[t] = attn[(size_t)b * 256 + t];
    __syncthreads();
    int d = dc * 256 + t;
    size_t rowb = ((size_t)b * DV_ + d) * S_;
    float acc = 0.f;
    #pragma unroll 7
    for (int i = 0; i < 49; ++i) {
        F4 u = ld4(iv, rowb + 4 * i, f);
        acc += u.v[0] * at[4*i+0];
        acc += u.v[1] * at[4*i+1];
        acc += u.v[2] * at[4*i+2];
        acc += u.v[3] * at[4*i+3];
    }
    xvatt[(size_t)b * DV_ + d] = acc;
}

// ---------------------------------------------------------------------------
// Kernel 3c: v_feat = x_v_att @ W_img^T + b_img -> out[:, :1024]
// ---------------------------------------------------------------------------
__global__ __launch_bounds__(256) void k3c_vfeat(
    const float* __restrict__ xvatt, const void* __restrict__ Wimg,
    const void* __restrict__ bimg, void* __restrict__ out,
    const int* __restrict__ flags)
{
    const int f = flags[0];
    __shared__ float xv[DV_];
    int t = threadIdx.x;
    int oc = blockIdx.x >> 4, bc2 = blockIdx.x & 15;
    int o0 = oc * 64, b0 = bc2 * 16;
    int wave = t >> 6, lane = t & 63;
    for (int bb = 0; bb < 16; ++bb) {
        int b = b0 + bb;
        __syncthreads();
        {
            const float4* src = (const float4*)(xvatt + (size_t)b * DV_);
            float4* dst = (float4*)xv;
            dst[t] = src[t];
            dst[t + 256] = src[t + 256];
        }
        __syncthreads();
        for (int j = 0; j < 16; ++j) {
            int o = o0 + wave * 16 + j;
            size_t wrow = (size_t)o * DV_;
            float p = 0.f;
            #pragma unroll
            for (int i = 0; i < 4; ++i) {
                int c = 8 * lane + 512 * i;
                F8 u = ld8(Wimg, wrow + c, f);
                p += u.v[0]*xv[c+0] + u.v[1]*xv[c+1] + u.v[2]*xv[c+2] + u.v[3]*xv[c+3];
                p += u.v[4]*xv[c+4] + u.v[5]*xv[c+5] + u.v[6]*xv[c+6] + u.v[7]*xv[c+7];
            }
            #pragma unroll
            for (int off = 1; off < 64; off <<= 1)
                p += __shfl_xor(p, off, 64);
            if (lane == 0)
                stout(out, (size_t)b * 2048 + o, p + lds1(bimg, o, f), f);
        }
    }
}

// ---------------------------------------------------------------------------
extern "C" void kernel_launch(void* const* d_in, const int* in_sizes, int n_in,
                              void* d_out, int out_size, void* d_ws, size_t ws_size,
                              hipStream_t stream)
{
    const void* iv   = d_in[0];   // input_v  [256,2048,196]
    const void* emb  = d_in[1];   // emb      [3000,620]
    const void* Wc   = d_in[2];   // W_conv_v [1200,2048]
    const void* bcv  = d_in[3];   // b_conv_v [1200]
    const void* Wla  = d_in[4];   // W_lin_a  [1200,620]
    const void* bla  = d_in[5];   // b_lin_a  [1200]
    const void* watt = d_in[6];   // w_att    [1200]
    // d_in[7] = b_att: softmax shift-invariant, unused
    const void* Wimg = d_in[8];   // W_img    [1024,2048]
    const void* bimg = d_in[9];   // b_img    [1024]
    const void* Wans = d_in[10];  // W_ans    [1024,620]
    const void* bans = d_in[11];  // b_ans    [1024]
    const int*  ia   = (const int*)d_in[12];  // input_a [256] int32

    char* ws = (char*)d_ws;
    float* xa_w   = (float*)(ws);                      // 1,310,720 B
    float* logits = (float*)(ws + 1310720);            //   262,144 B
    float* xvatt  = (float*)(ws + 1572864);            // 2,097,152 B
    int*   flags  = (int*)(ws + 3670016);              //     4,096 B
    ushort_t* Wcb = (ushort_t*)(ws + 3674112);         // 5,242,880 B
    ushort_t* ivb = (ushort_t*)(ws + 8916992);         // 234,881,024 B
    const size_t WS_NEED = 8916992ull + (size_t)B_ * IVB_SSTR * DV_ * 2;

    hipMemsetAsync(logits, 0, 256 * 256 * 4, stream);
    k0_detect<<<1, 64, 0, stream>>>(emb, flags);
    k1_xa<<<256, 256, 0, stream>>>(emb, ia, Wla, bla, watt, Wans, bans, xa_w, d_out, flags);
    if (ws_size >= WS_NEED) {
        kp_w<<<1280, 256, 0, stream>>>(Wc, Wcb, flags);
        kp_iv<<<32768, 256, 0, stream>>>(iv, ivb, flags);
        k2_gemm_v2<<<5120, 256, 0, stream>>>(ivb, Wcb, bcv, xa_w, logits, flags);
    } else {
        k2_gemm<<<5120, 256, 0, stream>>>(iv, Wc, bcv, xa_w, logits, flags);
    }
    k3a_softmax<<<256, 64, 0, stream>>>(logits);
    k3b_wsum<<<2048, 256, 0, stream>>>(iv, logits, xvatt, flags);
    k3c_vfeat<<<256, 256, 0, stream>>>(xvatt, Wimg, bimg, d_out, flags);
}

// Round 2
// 1364.595 us; speedup vs baseline: 1.6142x; 1.2343x over previous
//
#include <hip/hip_runtime.h>
#include <cstdint>
#include <cstddef>

// Problem constants
#define B_     256
#define S_     196
#define DV_    2048
#define DA_    620
#define DATT_  1200
#define DATTP_ 1280   // DATT padded to 10 * BN
#define DOUT_  1024

#define IVB_SSTR 224  // per-b row padding for bf16 transposed input (>= 112+112)

typedef unsigned short ushort_t;
typedef __attribute__((ext_vector_type(8))) short short8;
typedef __attribute__((ext_vector_type(4))) float floatx4;

__device__ __forceinline__ float bf2f(unsigned int u) {
    union { unsigned int i; float f; } v; v.i = u << 16; return v.f;
}
__device__ __forceinline__ ushort_t f2bf(float x) {   // RNE f32->bf16
    union { float f; unsigned int u; } c; c.f = x;
    unsigned int r = (c.u + 0x7fffu + ((c.u >> 16) & 1u)) >> 16;
    return (ushort_t)r;
}

struct F4 { float v[4]; };
struct F8 { float v[8]; };

// Generic input loaders: f=1 -> fp32 buffer, f=0 -> bf16 buffer. i = element idx.
__device__ __forceinline__ F4 ld4(const void* p, size_t i, int f) {
    F4 r;
    if (f) {
        float4 u = *(const float4*)((const float*)p + i);
        r.v[0]=u.x; r.v[1]=u.y; r.v[2]=u.z; r.v[3]=u.w;
    } else {
        uint2 u = *(const uint2*)((const ushort_t*)p + i);
        r.v[0]=bf2f(u.x & 0xffffu); r.v[1]=bf2f(u.x >> 16);
        r.v[2]=bf2f(u.y & 0xffffu); r.v[3]=bf2f(u.y >> 16);
    }
    return r;
}
__device__ __forceinline__ F8 ld8(const void* p, size_t i, int f) {
    F8 r;
    if (f) {
        float4 a = *(const float4*)((const float*)p + i);
        float4 b = *(const float4*)((const float*)p + i + 4);
        r.v[0]=a.x; r.v[1]=a.y; r.v[2]=a.z; r.v[3]=a.w;
        r.v[4]=b.x; r.v[5]=b.y; r.v[6]=b.z; r.v[7]=b.w;
    } else {
        uint4 u = *(const uint4*)((const ushort_t*)p + i);
        r.v[0]=bf2f(u.x & 0xffffu); r.v[1]=bf2f(u.x >> 16);
        r.v[2]=bf2f(u.y & 0xffffu); r.v[3]=bf2f(u.y >> 16);
        r.v[4]=bf2f(u.z & 0xffffu); r.v[5]=bf2f(u.z >> 16);
        r.v[6]=bf2f(u.w & 0xffffu); r.v[7]=bf2f(u.w >> 16);
    }
    return r;
}
__device__ __forceinline__ float lds1(const void* p, size_t i, int f) {
    return f ? ((const float*)p)[i] : bf2f((unsigned int)((const ushort_t*)p)[i]);
}
__device__ __forceinline__ void stout(void* p, size_t i, float v, int f) {
    if (f) ((float*)p)[i] = v; else ((ushort_t*)p)[i] = f2bf(v);
}

// async 16B global->LDS copy (wave-uniform LDS base + lane*16, per-lane src)
typedef const __attribute__((address_space(1))) unsigned int* gas_t;
typedef __attribute__((address_space(3))) unsigned int* las_t;
__device__ __forceinline__ void async_cp16(const ushort_t* src, ushort_t* lds) {
    __builtin_amdgcn_global_load_lds((gas_t)(const void*)src, (las_t)(void*)lds, 16, 0, 0);
}

// ---------------------------------------------------------------------------
// Kernel 0: dtype detector. emb ~ N(0,1). bf16 data: ~64/64 ushorts have sane
// bf16 exponents (100..140). fp32 data: only the 32 high halves do (~37/64).
// ---------------------------------------------------------------------------
__global__ __launch_bounds__(64) void k0_detect(const void* __restrict__ emb,
                                                int* __restrict__ flags)
{
    int lane = threadIdx.x;
    unsigned int u = ((const ushort_t*)emb)[lane];
    unsigned int e = (u >> 7) & 0xffu;
    bool sane = (e >= 100u && e <= 140u);
    unsigned long long m = __ballot(sane);
    if (lane == 0) flags[0] = (__popcll(m) >= 48) ? 0 : 1;   // 0=bf16, 1=fp32
}

// ---------------------------------------------------------------------------
// Kernel 1: x_a_vec gather + xa_w = relu(x_a_vec @ W_lin_a^T + b)*w_att (padded
// to 1280 with zeros) and a_feat = x_a_vec @ W_ans^T + b_ans -> out[:,1024:]
// grid 512 = bchunk(16) x rowchunk(32, 72 rows each) -> 2 blocks/CU.
// ---------------------------------------------------------------------------
__global__ __launch_bounds__(256) void k1_xa(
    const void* __restrict__ emb, const int* __restrict__ ia,
    const void* __restrict__ Wla, const void* __restrict__ bla,
    const void* __restrict__ watt,
    const void* __restrict__ Wans, const void* __restrict__ bans,
    float* __restrict__ xa_w, void* __restrict__ out,
    const int* __restrict__ flags)
{
    const int f = flags[0];
    __shared__ float xa[16][DA_];
    int t = threadIdx.x;
    int bc = blockIdx.x & 15, rc = blockIdx.x >> 4;   // rc 0..31
    int b0 = bc * 16;
    for (int idx = t; idx < 16 * 155; idx += 256) {
        int row = idx / 155, c8 = idx % 155;
        int cls = ia[b0 + row];
        cls = min(max(cls, 0), 2999);
        F4 u = ld4(emb, (size_t)cls * DA_ + c8 * 4, f);
        xa[row][c8*4+0] = u.v[0]; xa[row][c8*4+1] = u.v[1];
        xa[row][c8*4+2] = u.v[2]; xa[row][c8*4+3] = u.v[3];
    }
    __syncthreads();
    int wave = t >> 6, lane = t & 63;
    for (int j = 0; j < 18; ++j) {
        int row = rc * 72 + wave + 4 * j;   // 0..2303
        bool is_xa = row < DATTP_;
        int n = row;
        int o = row - DATTP_;
        const void* wmat = is_xa ? Wla : Wans;
        size_t wrow = is_xa ? (size_t)n * DA_ : (size_t)o * DA_;
        bool live = !(is_xa && n >= DATT_);
        float wv[12];
        if (live) {
            #pragma unroll
            for (int i = 0; i < 3; ++i) {
                int c = 4 * lane + 256 * i;
                if (c < DA_) {
                    F4 u = ld4(wmat, wrow + c, f);
                    wv[i*4+0]=u.v[0]; wv[i*4+1]=u.v[1];
                    wv[i*4+2]=u.v[2]; wv[i*4+3]=u.v[3];
                } else { wv[i*4+0]=0.f; wv[i*4+1]=0.f; wv[i*4+2]=0.f; wv[i*4+3]=0.f; }
            }
        }
        for (int bb = 0; bb < 16; ++bb) {
            float p = 0.f;
            if (live) {
                #pragma unroll
                for (int i = 0; i < 3; ++i) {
                    int c = 4 * lane + 256 * i;
                    if (c < DA_) {
                        p += wv[i*4+0]*xa[bb][c+0] + wv[i*4+1]*xa[bb][c+1]
                           + wv[i*4+2]*xa[bb][c+2] + wv[i*4+3]*xa[bb][c+3];
                    }
                }
            }
            #pragma unroll
            for (int off = 1; off < 64; off <<= 1)
                p += __shfl_xor(p, off, 64);
            if (lane == 0) {
                int b = b0 + bb;
                if (is_xa) {
                    float v = 0.f;
                    if (n < DATT_)
                        v = fmaxf(p + lds1(bla, n, f), 0.f) * lds1(watt, n, f);
                    xa_w[(size_t)b * DATTP_ + n] = v;
                } else {
                    stout(out, (size_t)b * 2048 + 1024 + o,
                          p + lds1(bans, o, f), f);
                }
            }
        }
    }
}

// ---------------------------------------------------------------------------
// Prepass W: Wcb[n][c] = bf16(W_conv_v[n][c]), rows 1200..1279 zeroed.
// ---------------------------------------------------------------------------
__global__ __launch_bounds__(256) void kp_w(
    const void* __restrict__ Wc, ushort_t* __restrict__ Wcb,
    const int* __restrict__ flags)
{
    const int f = flags[0];
    int n = blockIdx.x;                 // 0..1279
    int t = threadIdx.x;
    size_t o = (size_t)n * DV_ + t * 8;
    uint4 w = make_uint4(0u, 0u, 0u, 0u);
    if (n < DATT_) {
        F8 u = ld8(Wc, o, f);
        w.x = (unsigned)f2bf(u.v[0]) | ((unsigned)f2bf(u.v[1]) << 16);
        w.y = (unsigned)f2bf(u.v[2]) | ((unsigned)f2bf(u.v[3]) << 16);
        w.z = (unsigned)f2bf(u.v[4]) | ((unsigned)f2bf(u.v[5]) << 16);
        w.w = (unsigned)f2bf(u.v[6]) | ((unsigned)f2bf(u.v[7]) << 16);
    }
    *(uint4*)&Wcb[o] = w;
}

// ---------------------------------------------------------------------------
// Prepass iv: ivb[b][s][c] = bf16(input_v[b][c][s]).  64c x 64s LDS tiles,
// 16B-unit XOR swizzle -> both LDS sides conflict-free, both global sides
// coalesced. Rows s in [196,224) left unwritten (garbage ok: GEMM output rows
// for s>=196 are never stored).
// ---------------------------------------------------------------------------
__global__ __launch_bounds__(256) void kp_iv(
    const void* __restrict__ iv, ushort_t* __restrict__ ivb,
    const int* __restrict__ flags)
{
    const int f = flags[0];
    __shared__ float tile[64 * 64];
    int t = threadIdx.x;
    int bid = blockIdx.x;
    int b  = bid >> 7;
    int cc = (bid >> 2) & 31;
    int sc = bid & 3;
    int c0 = cc * 64, s0 = sc * 64;
    #pragma unroll
    for (int i = 0; i < 4; ++i) {
        int idx = t + 256 * i;
        int c = idx >> 4, q = idx & 15;
        int s = s0 + 4 * q;
        float4 v = make_float4(0.f, 0.f, 0.f, 0.f);
        if (s < S_) {
            F4 u = ld4(iv, ((size_t)b * DV_ + (c0 + c)) * (size_t)S_ + s, f);
            v = make_float4(u.v[0], u.v[1], u.v[2], u.v[3]);
        }
        int up = q ^ (c >> 2);
        *(float4*)&tile[c * 64 + up * 4] = v;
    }
    __syncthreads();
    #pragma unroll
    for (int i = 0; i < 4; ++i) {
        int sl = (t >> 4) + 16 * i;          // local s row 0..63
        int s = s0 + sl;
        int g = t & 15;                      // 4 c's per thread
        if (s < S_) {
            int uw = ((sl >> 2) ^ g) << 2;
            ushort4 w;
            w.x = f2bf(tile[(4*g + 0) * 64 + uw + (sl & 3)]);
            w.y = f2bf(tile[(4*g + 1) * 64 + uw + (sl & 3)]);
            w.z = f2bf(tile[(4*g + 2) * 64 + uw + (sl & 3)]);
            w.w = f2bf(tile[(4*g + 3) * 64 + uw + (sl & 3)]);
            *(ushort4*)&ivb[(size_t)b * (IVB_SSTR * DV_) + (size_t)s * DV_ + c0 + 4*g] = w;
        }
    }
}

// ---------------------------------------------------------------------------
// Kernel 2 v3: fused conv-GEMM + logits reduction, DOUBLE-BUFFERED.
// T3-minimum 2-phase: issue stage(kt+1) into the other buffer BEFORE computing
// kt; one vmcnt(0)+barrier per K-step (compiler emits it in __syncthreads).
// LDS = 2*(14336+16384)+448 = ~62KB -> 2 blocks/CU; in-flight prefetch
// replaces the lost TLP.
// ---------------------------------------------------------------------------
#define BM2_ 112
#define BN2_ 128

template<int MT>
__device__ __forceinline__ void k2_body(
    const ushort_t* __restrict__ ivA,   // ivb + b*IVB_SSTR*2048 + s0*2048
    const ushort_t* __restrict__ Bp,    // Wcb + n0*2048
    const void* __restrict__ bcv, const float* __restrict__ xa_w,
    float* __restrict__ logits, int f,
    ushort_t* sA0, ushort_t* sA1, ushort_t* sB0, ushort_t* sB1,
    float* llog, int b, int s0, int n0, int rows_valid, int t)
{
    const int A_units = MT * 16 * 8;            // 16B units in A tile (mult of 64)
    const int total_units = A_units + BN2_ * 8;
    int wave = t >> 6, lane = t & 63;
    int lquad = lane >> 4, l15 = lane & 15;
    int nbase = wave * 32;                      // 2 n-tiles per wave

    floatx4 acc[MT][2];
    #pragma unroll
    for (int mt = 0; mt < MT; ++mt) {
        acc[mt][0] = floatx4{0.f, 0.f, 0.f, 0.f};
        acc[mt][1] = floatx4{0.f, 0.f, 0.f, 0.f};
    }

    auto stage = [&](const ushort_t* aK, const ushort_t* bK,
                     ushort_t* dA, ushort_t* dB) {
        #pragma unroll
        for (int u0 = 0; u0 < total_units; u0 += 256) {
            int u = u0 + t;
            if (u < total_units) {
                int ub = u & ~63;               // wave-uniform LDS base unit
                if (u < A_units) {
                    int r = u >> 3, up = u & 7, ul = up ^ (r & 7);
                    async_cp16(aK + (size_t)r * DV_ + ul * 8, dA + ub * 8);
                } else {
                    int v = u - A_units;
                    int r = v >> 3, up = v & 7, ul = up ^ (r & 7);
                    async_cp16(bK + (size_t)r * DV_ + ul * 8, dB + (ub - A_units) * 8);
                }
            }
        }
    };

    auto compute = [&](const ushort_t* cA, const ushort_t* cB) {
        #pragma unroll
        for (int ks = 0; ks < 2; ++ks) {
            int usw = (ks * 4 + lquad) ^ (l15 & 7);   // row&7 == l15&7 for all tiles
            short8 bf0 = *(const short8*)&cB[((nbase      + l15) * 8 + usw) * 8];
            short8 bf1 = *(const short8*)&cB[((nbase + 16 + l15) * 8 + usw) * 8];
            #pragma unroll
            for (int mt = 0; mt < MT; ++mt) {
                short8 af = *(const short8*)&cA[((mt * 16 + l15) * 8 + usw) * 8];
                acc[mt][0] = __builtin_amdgcn_mfma_f32_16x16x32_bf16(af, bf0, acc[mt][0], 0, 0, 0);
                acc[mt][1] = __builtin_amdgcn_mfma_f32_16x16x32_bf16(af, bf1, acc[mt][1], 0, 0, 0);
            }
        }
    };

    // prologue: fill buffer 0 for kt=0
    stage(ivA, Bp, sA0, sB0);
    __syncthreads();                            // drains vmcnt(0)
    // main loop, unrolled x2 so buffer pointers are static
    for (int kt = 0; kt < 32; kt += 2) {
        // even step: compute buf0, prefetch kt+1 into buf1
        stage(ivA + (kt + 1) * 64, Bp + (kt + 1) * 64, sA1, sB1);
        compute(sA0, sB0);
        __syncthreads();                        // vmcnt(0): stage(kt+1) landed
        // odd step: compute buf1, prefetch kt+2 into buf0
        if (kt + 2 < 32)
            stage(ivA + (kt + 2) * 64, Bp + (kt + 2) * 64, sA0, sB0);
        compute(sA1, sB1);
        __syncthreads();
    }

    // Epilogue: relu(acc + bias) * xa_w, reduce over n.
    // C/D layout (16x16x32): col(n) = lane&15, row(s) = (lane>>4)*4 + reg.
    float bias[2], xw[2];
    #pragma unroll
    for (int bt = 0; bt < 2; ++bt) {
        int ng = n0 + nbase + bt * 16 + l15;
        bias[bt] = (ng < DATT_) ? lds1(bcv, ng, f) : 0.f;
        xw[bt]   = (ng < DATT_) ? xa_w[(size_t)b * DATTP_ + ng] : 0.f;
    }
    float plog[MT][4];
    #pragma unroll
    for (int mt = 0; mt < MT; ++mt)
        #pragma unroll
        for (int r = 0; r < 4; ++r) {
            float v0 = fmaxf(acc[mt][0][r] + bias[0], 0.f) * xw[0];
            float v1 = fmaxf(acc[mt][1][r] + bias[1], 0.f) * xw[1];
            plog[mt][r] = v0 + v1;
        }
    #pragma unroll
    for (int off = 1; off <= 8; off <<= 1)
        #pragma unroll
        for (int mt = 0; mt < MT; ++mt)
            #pragma unroll
            for (int r = 0; r < 4; ++r)
                plog[mt][r] += __shfl_xor(plog[mt][r], off, 64);
    if (l15 == 0) {
        #pragma unroll
        for (int mt = 0; mt < MT; ++mt)
            #pragma unroll
            for (int r = 0; r < 4; ++r)
                atomicAdd(&llog[mt * 16 + lquad * 4 + r], plog[mt][r]);
    }
    __syncthreads();
    if (t < rows_valid)
        atomicAdd(&logits[(size_t)b * 256 + s0 + t], llog[t]);
}

__global__ __launch_bounds__(256) void k2_gemm_v2(
    const ushort_t* __restrict__ ivb, const ushort_t* __restrict__ Wcb,
    const void* __restrict__ bcv, const float* __restrict__ xa_w,
    float* __restrict__ logits, const int* __restrict__ flags)
{
    const int f = flags[0];
    __shared__ ushort_t sA[2][BM2_ * 64];
    __shared__ ushort_t sB[2][BN2_ * 64];
    __shared__ float llog[BM2_];
    int t = threadIdx.x;
    int bid = blockIdx.x;
    // bijective XCD swizzle (5120 % 8 == 0): each XCD gets 640 consecutive
    // logical ids = 32 b's worth of blocks -> per-b A panel stays in that L2.
    int lg = (bid & 7) * 640 + (bid >> 3);
    int b = lg / 20, rem = lg % 20;
    int mb = rem / 10, nb = rem % 10;
    int s0 = mb * BM2_, n0 = nb * BN2_;
    int rows_valid = min(BM2_, S_ - s0);       // 112 or 84
    if (t < BM2_) llog[t] = 0.f;
    const ushort_t* ivA = ivb + (size_t)b * (IVB_SSTR * DV_) + (size_t)s0 * DV_;
    const ushort_t* Bp  = Wcb + (size_t)n0 * DV_;
    if (mb == 0)
        k2_body<7>(ivA, Bp, bcv, xa_w, logits, f,
                   sA[0], sA[1], sB[0], sB[1], llog, b, s0, n0, rows_valid, t);
    else
        k2_body<6>(ivA, Bp, bcv, xa_w, logits, f,
                   sA[0], sA[1], sB[0], sB[1], llog, b, s0, n0, rows_valid, t);
}

// ---------------------------------------------------------------------------
// Kernel 2 fallback (workspace too small): original fused conv-GEMM.
// ---------------------------------------------------------------------------
#define BM_  112
#define BN_  128
#define LDA_ 40
#define LDB_ 40

__global__ __launch_bounds__(256) void k2_gemm(
    const void* __restrict__ iv, const void* __restrict__ Wc,
    const void* __restrict__ bcv, const float* __restrict__ xa_w,
    float* __restrict__ logits, const int* __restrict__ flags)
{
    const int f = flags[0];
    __shared__ ushort_t Al[BM_ * LDA_];
    __shared__ ushort_t Bl[BN_ * LDB_];
    __shared__ float llog[BM_];

    int t = threadIdx.x;
    int bid = blockIdx.x;
    int b   = bid / 20;
    int rem = bid % 20;
    int mb = rem / 10, nb = rem % 10;
    int s0 = mb * BM_, n0 = nb * BN_;
    int rows_valid = min(BM_, S_ - s0);
    int cpc = (rows_valid + 7) >> 3;
    int totA = 32 * cpc;

    if (t < BM_) llog[t] = 0.f;
    for (int idx = t; idx < (BM_ - rows_valid) * LDA_; idx += 256)
        Al[rows_valid * LDA_ + idx] = 0;

    size_t ivbase = (size_t)b * DV_ * S_;

    int wave = t >> 6, lane = t & 63;
    int lquad = lane >> 4, l15 = lane & 15;
    int nbase = wave * 32;

    floatx4 acc[7][2];
    #pragma unroll
    for (int mt = 0; mt < 7; ++mt) {
        acc[mt][0] = floatx4{0.f, 0.f, 0.f, 0.f};
        acc[mt][1] = floatx4{0.f, 0.f, 0.f, 0.f};
    }

    for (int kt = 0; kt < DV_ / 32; ++kt) {
        int k0 = kt * 32;
        __syncthreads();
        for (int idx = t; idx < totA; idx += 256) {
            int c = idx & 31, j = idx >> 5;
            int sr = min(8 * j, rows_valid - 8);
            F8 u = ld8(iv, ivbase + (size_t)(k0 + c) * S_ + s0 + sr, f);
            #pragma unroll
            for (int i = 0; i < 8; ++i)
                Al[(sr + i) * LDA_ + c] = f2bf(u.v[i]);
        }
        for (int idx = t; idx < 512; idx += 256) {
            int nl = idx >> 2, kc = idx & 3;
            int ng = n0 + nl;
            if (ng < DATT_) {
                F8 u = ld8(Wc, (size_t)ng * DV_ + k0 + kc * 8, f);
                #pragma unroll
                for (int i = 0; i < 8; ++i)
                    Bl[nl * LDB_ + kc * 8 + i] = f2bf(u.v[i]);
            } else {
                #pragma unroll
                for (int i = 0; i < 8; ++i)
                    Bl[nl * LDB_ + kc * 8 + i] = 0;
            }
        }
        __syncthreads();
        short8 bf0 = *(const short8*)&Bl[(nbase + l15) * LDB_ + lquad * 8];
        short8 bf1 = *(const short8*)&Bl[(nbase + 16 + l15) * LDB_ + lquad * 8];
        #pragma unroll
        for (int mt = 0; mt < 7; ++mt) {
            short8 af = *(const short8*)&Al[(mt * 16 + l15) * LDA_ + lquad * 8];
            acc[mt][0] = __builtin_amdgcn_mfma_f32_16x16x32_bf16(af, bf0, acc[mt][0], 0, 0, 0);
            acc[mt][1] = __builtin_amdgcn_mfma_f32_16x16x32_bf16(af, bf1, acc[mt][1], 0, 0, 0);
        }
    }

    float bias[2], xw[2];
    #pragma unroll
    for (int bt = 0; bt < 2; ++bt) {
        int ng = n0 + nbase + bt * 16 + l15;
        bias[bt] = (ng < DATT_) ? lds1(bcv, ng, f) : 0.f;
        xw[bt]   = (ng < DATT_) ? xa_w[(size_t)b * DATTP_ + ng] : 0.f;
    }
    float plog[7][4];
    #pragma unroll
    for (int mt = 0; mt < 7; ++mt)
        #pragma unroll
        for (int r = 0; r < 4; ++r) {
            float v0 = fmaxf(acc[mt][0][r] + bias[0], 0.f) * xw[0];
            float v1 = fmaxf(acc[mt][1][r] + bias[1], 0.f) * xw[1];
            plog[mt][r] = v0 + v1;
        }
    #pragma unroll
    for (int off = 1; off <= 8; off <<= 1)
        #pragma unroll
        for (int mt = 0; mt < 7; ++mt)
            #pragma unroll
            for (int r = 0; r < 4; ++r)
                plog[mt][r] += __shfl_xor(plog[mt][r], off, 64);
    if (l15 == 0) {
        #pragma unroll
        for (int mt = 0; mt < 7; ++mt)
            #pragma unroll
            for (int r = 0; r < 4; ++r)
                atomicAdd(&llog[mt * 16 + lquad * 4 + r], plog[mt][r]);
    }
    __syncthreads();
    if (t < rows_valid)
        atomicAdd(&logits[(size_t)b * 256 + s0 + t], llog[t]);
}

// ---------------------------------------------------------------------------
// Kernel 3a: softmax over s (196) per b, IN PLACE.
// ---------------------------------------------------------------------------
__global__ __launch_bounds__(64) void k3a_softmax(float* __restrict__ logits)
{
    int b = blockIdx.x, lane = threadIdx.x;
    float v[4]; float mx = -1e30f;
    #pragma unroll
    for (int i = 0; i < 4; ++i) {
        int s = lane + 64 * i;
        v[i] = (s < S_) ? logits[(size_t)b * 256 + s] : -1e30f;
        union { float f; unsigned u; } cv; cv.f = v[i];
        if ((cv.u & 0x7f800000u) == 0x7f800000u) v[i] = -1e30f;
        mx = fmaxf(mx, v[i]);
    }
    #pragma unroll
    for (int off = 1; off < 64; off <<= 1)
        mx = fmaxf(mx, __shfl_xor(mx, off, 64));
    float e[4]; float sum = 0.f;
    #pragma unroll
    for (int i = 0; i < 4; ++i) {
        int s = lane + 64 * i;
        e[i] = (s < S_) ? __expf(v[i] - mx) : 0.f;
        sum += e[i];
    }
    #pragma unroll
    for (int off = 1; off < 64; off <<= 1)
        sum += __shfl_xor(sum, off, 64);
    float inv = 1.f / sum;
    #pragma unroll
    for (int i = 0; i < 4; ++i) {
        int s = lane + 64 * i;
        if (s < S_) logits[(size_t)b * 256 + s] = e[i] * inv;
    }
}

// ---------------------------------------------------------------------------
// Kernel 3b: x_v_att[b,d] = sum_s attn[b,s] * input_v[b,d,s]
// Wave-per-row: 49 lanes x 16B = one contiguous 784B row read per wave-instr
// (was: thread-per-row, 64 lanes scattered across 64 cache lines).
// grid 2048 = b(256) x dchunk(8), block 256 (4 waves, 64 rows each)
// ---------------------------------------------------------------------------
__global__ __launch_bounds__(256) void k3b_wsum(
    const void* __restrict__ iv, const float* __restrict__ attn,
    float* __restrict__ xvatt, const int* __restrict__ flags)
{
    const int f = flags[0];
    __shared__ float at[200];
    int t = threadIdx.x;
    int b = blockIdx.x >> 3, dc = blockIdx.x & 7;
    if (t < S_) at[t] = attn[(size_t)b * 256 + t];
    __syncthreads();
    int wave = t >> 6, lane = t & 63;
    int s = 4 * lane;                       // lanes 0..48 active (4*49 = 196)
    float a0 = 0.f, a1 = 0.f, a2 = 0.f, a3 = 0.f;
    if (s < S_) { a0 = at[s]; a1 = at[s+1]; a2 = at[s+2]; a3 = at[s+3]; }
    int dbase = dc * 256 + wave * 64;
    size_t rowb = ((size_t)b * DV_ + dbase) * S_;
    #pragma unroll 4
    for (int rr = 0; rr < 64; ++rr) {
        float p = 0.f;
        if (s < S_) {
            F4 u = ld4(iv, rowb + (size_t)rr * S_ + s, f);
            p = u.v[0]*a0 + u.v[1]*a1 + u.v[2]*a2 + u.v[3]*a3;
        }
        #pragma unroll
        for (int off = 1; off < 64; off <<= 1)
            p += __shfl_xor(p, off, 64);
        if (lane == 0) xvatt[(size_t)b * DV_ + dbase + rr] = p;
    }
}

// ---------------------------------------------------------------------------
// Kernel 3c: v_feat = x_v_att @ W_img^T + b_img -> out[:, :1024]
// grid 512 = ochunk(16, 64 rows) x bchunk(32, 8 b) -> 2 blocks/CU
// ---------------------------------------------------------------------------
__global__ __launch_bounds__(256) void k3c_vfeat(
    const float* __restrict__ xvatt, const void* __restrict__ Wimg,
    const void* __restrict__ bimg, void* __restrict__ out,
    const int* __restrict__ flags)
{
    const int f = flags[0];
    __shared__ float xv[DV_];
    int t = threadIdx.x;
    int oc = blockIdx.x >> 5, bc2 = blockIdx.x & 31;
    int o0 = oc * 64, b0 = bc2 * 8;
    int wave = t >> 6, lane = t & 63;
    for (int bb = 0; bb < 8; ++bb) {
        int b = b0 + bb;
        __syncthreads();
        {
            const float4* src = (const float4*)(xvatt + (size_t)b * DV_);
            float4* dst = (float4*)xv;
            dst[t] = src[t];
            dst[t + 256] = src[t + 256];
        }
        __syncthreads();
        for (int j = 0; j < 16; ++j) {
            int o = o0 + wave * 16 + j;
            size_t wrow = (size_t)o * DV_;
            float p = 0.f;
            #pragma unroll
            for (int i = 0; i < 4; ++i) {
                int c = 8 * lane + 512 * i;
                F8 u = ld8(Wimg, wrow + c, f);
                p += u.v[0]*xv[c+0] + u.v[1]*xv[c+1] + u.v[2]*xv[c+2] + u.v[3]*xv[c+3];
                p += u.v[4]*xv[c+4] + u.v[5]*xv[c+5] + u.v[6]*xv[c+6] + u.v[7]*xv[c+7];
            }
            #pragma unroll
            for (int off = 1; off < 64; off <<= 1)
                p += __shfl_xor(p, off, 64);
            if (lane == 0)
                stout(out, (size_t)b * 2048 + o, p + lds1(bimg, o, f), f);
        }
    }
}

// ---------------------------------------------------------------------------
extern "C" void kernel_launch(void* const* d_in, const int* in_sizes, int n_in,
                              void* d_out, int out_size, void* d_ws, size_t ws_size,
                              hipStream_t stream)
{
    const void* iv   = d_in[0];   // input_v  [256,2048,196]
    const void* emb  = d_in[1];   // emb      [3000,620]
    const void* Wc   = d_in[2];   // W_conv_v [1200,2048]
    const void* bcv  = d_in[3];   // b_conv_v [1200]
    const void* Wla  = d_in[4];   // W_lin_a  [1200,620]
    const void* bla  = d_in[5];   // b_lin_a  [1200]
    const void* watt = d_in[6];   // w_att    [1200]
    // d_in[7] = b_att: softmax shift-invariant, unused
    const void* Wimg = d_in[8];   // W_img    [1024,2048]
    const void* bimg = d_in[9];   // b_img    [1024]
    const void* Wans = d_in[10];  // W_ans    [1024,620]
    const void* bans = d_in[11];  // b_ans    [1024]
    const int*  ia   = (const int*)d_in[12];  // input_a [256] int32

    char* ws = (char*)d_ws;
    float* xa_w   = (float*)(ws);                      // 1,310,720 B
    float* logits = (float*)(ws + 1310720);            //   262,144 B
    float* xvatt  = (float*)(ws + 1572864);            // 2,097,152 B
    int*   flags  = (int*)(ws + 3670016);              //     4,096 B
    ushort_t* Wcb = (ushort_t*)(ws + 3674112);         // 5,242,880 B
    ushort_t* ivb = (ushort_t*)(ws + 8916992);         // 234,881,024 B
    const size_t WS_NEED = 8916992ull + (size_t)B_ * IVB_SSTR * DV_ * 2;

    hipMemsetAsync(logits, 0, 256 * 256 * 4, stream);
    k0_detect<<<1, 64, 0, stream>>>(emb, flags);
    k1_xa<<<512, 256, 0, stream>>>(emb, ia, Wla, bla, watt, Wans, bans, xa_w, d_out, flags);
    if (ws_size >= WS_NEED) {
        kp_w<<<1280, 256, 0, stream>>>(Wc, Wcb, flags);
        kp_iv<<<32768, 256, 0, stream>>>(iv, ivb, flags);
        k2_gemm_v2<<<5120, 256, 0, stream>>>(ivb, Wcb, bcv, xa_w, logits, flags);
    } else {
        k2_gemm<<<5120, 256, 0, stream>>>(iv, Wc, bcv, xa_w, logits, flags);
    }
    k3a_softmax<<<256, 64, 0, stream>>>(logits);
    k3b_wsum<<<2048, 256, 0, stream>>>(iv, logits, xvatt, flags);
    k3c_vfeat<<<512, 256, 0, stream>>>(xvatt, Wimg, bimg, d_out, flags);
}

// Round 4
// 1335.931 us; speedup vs baseline: 1.6488x; 1.0215x over previous
//
#include <hip/hip_runtime.h>
#include <cstdint>
#include <cstddef>

// Problem constants
#define B_     256
#define S_     196
#define DV_    2048
#define DA_    620
#define DATT_  1200
#define DATTP_ 1280   // DATT padded to 10 * 128 (= 5 * 256)
#define DOUT_  1024

#define IVB_SSTR 224  // per-b row padding for bf16 transposed input (>= 196)

typedef unsigned short ushort_t;
typedef __attribute__((ext_vector_type(8))) short short8;
typedef __attribute__((ext_vector_type(4))) float floatx4;
typedef __attribute__((ext_vector_type(16))) float floatx16;

__device__ __forceinline__ float bf2f(unsigned int u) {
    union { unsigned int i; float f; } v; v.i = u << 16; return v.f;
}
__device__ __forceinline__ ushort_t f2bf(float x) {   // RNE f32->bf16
    union { float f; unsigned int u; } c; c.f = x;
    unsigned int r = (c.u + 0x7fffu + ((c.u >> 16) & 1u)) >> 16;
    return (ushort_t)r;
}

struct F4 { float v[4]; };
struct F8 { float v[8]; };

// Generic input loaders: f=1 -> fp32 buffer, f=0 -> bf16 buffer. i = element idx.
__device__ __forceinline__ F4 ld4(const void* p, size_t i, int f) {
    F4 r;
    if (f) {
        float4 u = *(const float4*)((const float*)p + i);
        r.v[0]=u.x; r.v[1]=u.y; r.v[2]=u.z; r.v[3]=u.w;
    } else {
        uint2 u = *(const uint2*)((const ushort_t*)p + i);
        r.v[0]=bf2f(u.x & 0xffffu); r.v[1]=bf2f(u.x >> 16);
        r.v[2]=bf2f(u.y & 0xffffu); r.v[3]=bf2f(u.y >> 16);
    }
    return r;
}
__device__ __forceinline__ F8 ld8(const void* p, size_t i, int f) {
    F8 r;
    if (f) {
        float4 a = *(const float4*)((const float*)p + i);
        float4 b = *(const float4*)((const float*)p + i + 4);
        r.v[0]=a.x; r.v[1]=a.y; r.v[2]=a.z; r.v[3]=a.w;
        r.v[4]=b.x; r.v[5]=b.y; r.v[6]=b.z; r.v[7]=b.w;
    } else {
        uint4 u = *(const uint4*)((const ushort_t*)p + i);
        r.v[0]=bf2f(u.x & 0xffffu); r.v[1]=bf2f(u.x >> 16);
        r.v[2]=bf2f(u.y & 0xffffu); r.v[3]=bf2f(u.y >> 16);
        r.v[4]=bf2f(u.z & 0xffffu); r.v[5]=bf2f(u.z >> 16);
        r.v[6]=bf2f(u.w & 0xffffu); r.v[7]=bf2f(u.w >> 16);
    }
    return r;
}
__device__ __forceinline__ float lds1(const void* p, size_t i, int f) {
    return f ? ((const float*)p)[i] : bf2f((unsigned int)((const ushort_t*)p)[i]);
}
__device__ __forceinline__ void stout(void* p, size_t i, float v, int f) {
    if (f) ((float*)p)[i] = v; else ((ushort_t*)p)[i] = f2bf(v);
}

// async 16B global->LDS copy (wave-uniform LDS base + lane*16, per-lane src)
typedef const __attribute__((address_space(1))) unsigned int* gas_t;
typedef __attribute__((address_space(3))) unsigned int* las_t;
__device__ __forceinline__ void async_cp16(const ushort_t* src, ushort_t* lds) {
    __builtin_amdgcn_global_load_lds((gas_t)(const void*)src, (las_t)(void*)lds, 16, 0, 0);
}

// ---------------------------------------------------------------------------
// Kernel 0: dtype detector. emb ~ N(0,1). bf16 data: ~64/64 ushorts have sane
// bf16 exponents (100..140). fp32 data: only the 32 high halves do (~37/64).
// ---------------------------------------------------------------------------
__global__ __launch_bounds__(64) void k0_detect(const void* __restrict__ emb,
                                                int* __restrict__ flags)
{
    int lane = threadIdx.x;
    unsigned int u = ((const ushort_t*)emb)[lane];
    unsigned int e = (u >> 7) & 0xffu;
    bool sane = (e >= 100u && e <= 140u);
    unsigned long long m = __ballot(sane);
    if (lane == 0) flags[0] = (__popcll(m) >= 48) ? 0 : 1;   // 0=bf16, 1=fp32
}

// ---------------------------------------------------------------------------
// Kernel 1: x_a_vec gather + xa_w = relu(x_a_vec @ W_lin_a^T + b)*w_att (padded
// to 1280 with zeros) and a_feat = x_a_vec @ W_ans^T + b_ans -> out[:,1024:]
// grid 512 = bchunk(16) x rowchunk(32, 72 rows each) -> 2 blocks/CU.
// ---------------------------------------------------------------------------
__global__ __launch_bounds__(256) void k1_xa(
    const void* __restrict__ emb, const int* __restrict__ ia,
    const void* __restrict__ Wla, const void* __restrict__ bla,
    const void* __restrict__ watt,
    const void* __restrict__ Wans, const void* __restrict__ bans,
    float* __restrict__ xa_w, void* __restrict__ out,
    const int* __restrict__ flags)
{
    const int f = flags[0];
    __shared__ float xa[16][DA_];
    int t = threadIdx.x;
    int bc = blockIdx.x & 15, rc = blockIdx.x >> 4;   // rc 0..31
    int b0 = bc * 16;
    for (int idx = t; idx < 16 * 155; idx += 256) {
        int row = idx / 155, c8 = idx % 155;
        int cls = ia[b0 + row];
        cls = min(max(cls, 0), 2999);
        F4 u = ld4(emb, (size_t)cls * DA_ + c8 * 4, f);
        xa[row][c8*4+0] = u.v[0]; xa[row][c8*4+1] = u.v[1];
        xa[row][c8*4+2] = u.v[2]; xa[row][c8*4+3] = u.v[3];
    }
    __syncthreads();
    int wave = t >> 6, lane = t & 63;
    for (int j = 0; j < 18; ++j) {
        int row = rc * 72 + wave + 4 * j;   // 0..2303
        bool is_xa = row < DATTP_;
        int n = row;
        int o = row - DATTP_;
        const void* wmat = is_xa ? Wla : Wans;
        size_t wrow = is_xa ? (size_t)n * DA_ : (size_t)o * DA_;
        bool live = !(is_xa && n >= DATT_);
        float wv[12];
        if (live) {
            #pragma unroll
            for (int i = 0; i < 3; ++i) {
                int c = 4 * lane + 256 * i;
                if (c < DA_) {
                    F4 u = ld4(wmat, wrow + c, f);
                    wv[i*4+0]=u.v[0]; wv[i*4+1]=u.v[1];
                    wv[i*4+2]=u.v[2]; wv[i*4+3]=u.v[3];
                } else { wv[i*4+0]=0.f; wv[i*4+1]=0.f; wv[i*4+2]=0.f; wv[i*4+3]=0.f; }
            }
        }
        for (int bb = 0; bb < 16; ++bb) {
            float p = 0.f;
            if (live) {
                #pragma unroll
                for (int i = 0; i < 3; ++i) {
                    int c = 4 * lane + 256 * i;
                    if (c < DA_) {
                        p += wv[i*4+0]*xa[bb][c+0] + wv[i*4+1]*xa[bb][c+1]
                           + wv[i*4+2]*xa[bb][c+2] + wv[i*4+3]*xa[bb][c+3];
                    }
                }
            }
            #pragma unroll
            for (int off = 1; off < 64; off <<= 1)
                p += __shfl_xor(p, off, 64);
            if (lane == 0) {
                int b = b0 + bb;
                if (is_xa) {
                    float v = 0.f;
                    if (n < DATT_)
                        v = fmaxf(p + lds1(bla, n, f), 0.f) * lds1(watt, n, f);
                    xa_w[(size_t)b * DATTP_ + n] = v;
                } else {
                    stout(out, (size_t)b * 2048 + 1024 + o,
                          p + lds1(bans, o, f), f);
                }
            }
        }
    }
}

// ---------------------------------------------------------------------------
// Prepass W: Wcb[n][c] = bf16(W_conv_v[n][c]), rows 1200..1279 zeroed.
// ---------------------------------------------------------------------------
__global__ __launch_bounds__(256) void kp_w(
    const void* __restrict__ Wc, ushort_t* __restrict__ Wcb,
    const int* __restrict__ flags)
{
    const int f = flags[0];
    int n = blockIdx.x;                 // 0..1279
    int t = threadIdx.x;
    size_t o = (size_t)n * DV_ + t * 8;
    uint4 w = make_uint4(0u, 0u, 0u, 0u);
    if (n < DATT_) {
        F8 u = ld8(Wc, o, f);
        w.x = (unsigned)f2bf(u.v[0]) | ((unsigned)f2bf(u.v[1]) << 16);
        w.y = (unsigned)f2bf(u.v[2]) | ((unsigned)f2bf(u.v[3]) << 16);
        w.z = (unsigned)f2bf(u.v[4]) | ((unsigned)f2bf(u.v[5]) << 16);
        w.w = (unsigned)f2bf(u.v[6]) | ((unsigned)f2bf(u.v[7]) << 16);
    }
    *(uint4*)&Wcb[o] = w;
}

// ---------------------------------------------------------------------------
// Prepass iv: ivb[b][s][c] = bf16(input_v[b][c][s]).  64c x 64s LDS tiles,
// 16B-unit XOR swizzle -> both LDS sides conflict-free, both global sides
// coalesced. Rows s in [196,224) left unwritten (garbage ok: GEMM output rows
// for s>=196 are never stored).
// ---------------------------------------------------------------------------
__global__ __launch_bounds__(256) void kp_iv(
    const void* __restrict__ iv, ushort_t* __restrict__ ivb,
    const int* __restrict__ flags)
{
    const int f = flags[0];
    __shared__ float tile[64 * 64];
    int t = threadIdx.x;
    int bid = blockIdx.x;
    int b  = bid >> 7;
    int cc = (bid >> 2) & 31;
    int sc = bid & 3;
    int c0 = cc * 64, s0 = sc * 64;
    #pragma unroll
    for (int i = 0; i < 4; ++i) {
        int idx = t + 256 * i;
        int c = idx >> 4, q = idx & 15;
        int s = s0 + 4 * q;
        float4 v = make_float4(0.f, 0.f, 0.f, 0.f);
        if (s < S_) {
            F4 u = ld4(iv, ((size_t)b * DV_ + (c0 + c)) * (size_t)S_ + s, f);
            v = make_float4(u.v[0], u.v[1], u.v[2], u.v[3]);
        }
        int up = q ^ (c >> 2);
        *(float4*)&tile[c * 64 + up * 4] = v;
    }
    __syncthreads();
    #pragma unroll
    for (int i = 0; i < 4; ++i) {
        int sl = (t >> 4) + 16 * i;          // local s row 0..63
        int s = s0 + sl;
        int g = t & 15;                      // 4 c's per thread
        if (s < S_) {
            int uw = ((sl >> 2) ^ g) << 2;
            ushort4 w;
            w.x = f2bf(tile[(4*g + 0) * 64 + uw + (sl & 3)]);
            w.y = f2bf(tile[(4*g + 1) * 64 + uw + (sl & 3)]);
            w.z = f2bf(tile[(4*g + 2) * 64 + uw + (sl & 3)]);
            w.w = f2bf(tile[(4*g + 3) * 64 + uw + (sl & 3)]);
            *(ushort4*)&ivb[(size_t)b * (IVB_SSTR * DV_) + (size_t)s * DV_ + c0 + 4*g] = w;
        }
    }
}

// ---------------------------------------------------------------------------
// Kernel 2 v3: fused conv-GEMM + logits, 32x32x16 MFMA, one block per (b, nb).
// BM=256 (all of S, M-padded; rows 224..255 are unstaged LDS garbage,
// row-isolated in MFMA and never stored), BN=256, BK=64.
// 512 threads = 8 waves in a 2m x 4n grid; each wave computes 4 m-tiles x
// 2 n-tiles of 32x32 (acc = 128 VGPRs). Double-buffered LDS with prefetch.
// LDS layout: per 128B row, 16B units XOR-swizzled (unit ^= row&7);
// staged via global_load_lds(16) with inverse-swizzled source (rule 21).
// grid = 1280 = 256 b x 5 nb, XCD-swizzled (1280 % 8 == 0).
// ---------------------------------------------------------------------------
#define BM3_ 256
#define BN3_ 256
#define AU3_ 1792   // staged A units: 224 rows * 8  (multiple of 64)
#define BU3_ 2048   // B units: 256 rows * 8
#define TU3_ 3840   // total units per K-step

// ushort offsets into shared pool (region order matters: A overrun rows
// 224..255 read the following region -- in-bounds of the pool, garbage ok)
#define SA0_ 0
#define SA1_ 14336
#define SB0_ 28672
#define SB1_ 45056
#define SPOOL_ 61440

__global__ __launch_bounds__(512, 2) void k2_gemm_v3(
    const ushort_t* __restrict__ ivb, const ushort_t* __restrict__ Wcb,
    const void* __restrict__ bcv, const float* __restrict__ xa_w,
    float* __restrict__ logits, const int* __restrict__ flags)
{
    const int f = flags[0];
    __shared__ ushort_t smem[SPOOL_];
    __shared__ float llog[BM3_];
    int t = threadIdx.x;
    int bid = blockIdx.x;
    // bijective XCD swizzle: 1280 = 8 * 160; 5 consecutive lg = same b.
    int lg = (bid & 7) * 160 + (bid >> 3);
    int b = lg / 5, nb = lg % 5;
    int n0 = nb * BN3_;
    if (t < BM3_) llog[t] = 0.f;

    const ushort_t* ivA = ivb + (size_t)b * (IVB_SSTR * DV_);
    const ushort_t* Bp  = Wcb + (size_t)n0 * DV_;

    int w = t >> 6, lane = t & 63;
    int wm = w >> 2, wn = w & 3;         // wave grid: 2 m-groups x 4 n-groups
    int l31 = lane & 31, hi = lane >> 5, l7 = lane & 7;

    floatx16 acc[4][2];
    #pragma unroll
    for (int mt = 0; mt < 4; ++mt)
        #pragma unroll
        for (int nt = 0; nt < 2; ++nt)
            #pragma unroll
            for (int r = 0; r < 16; ++r)
                acc[mt][nt][r] = 0.f;

    auto stage = [&](const ushort_t* aK, const ushort_t* bK,
                     ushort_t* dA, ushort_t* dB) {
        #pragma unroll
        for (int u0 = 0; u0 < TU3_; u0 += 512) {
            int u = u0 + t;
            if (u < TU3_) {
                int ub = u & ~63;               // wave-uniform LDS base unit
                if (u < AU3_) {
                    int r = u >> 3, up = u & 7, ul = up ^ (r & 7);
                    async_cp16(aK + (size_t)r * DV_ + ul * 8, dA + ub * 8);
                } else {
                    int v = u - AU3_;
                    int r = v >> 3, up = v & 7, ul = up ^ (r & 7);
                    async_cp16(bK + (size_t)r * DV_ + ul * 8, dB + (v & ~63) * 8);
                }
            }
        }
    };

    auto compute = [&](const ushort_t* cA, const ushort_t* cB) {
        #pragma unroll
        for (int ks = 0; ks < 4; ++ks) {
            int lu = ks * 2 + hi;                 // logical 16B unit (k slice)
            int up = lu ^ l7;                     // row&7 == l7 for all tiles
            short8 af[4], bf[2];
            #pragma unroll
            for (int mt = 0; mt < 4; ++mt) {
                int row = wm * 128 + mt * 32 + l31;
                af[mt] = *(const short8*)&cA[row * 64 + up * 8];
            }
            #pragma unroll
            for (int nt = 0; nt < 2; ++nt) {
                int rn = wn * 64 + nt * 32 + l31;
                bf[nt] = *(const short8*)&cB[rn * 64 + up * 8];
            }
            #pragma unroll
            for (int mt = 0; mt < 4; ++mt)
                #pragma unroll
                for (int nt = 0; nt < 2; ++nt)
                    acc[mt][nt] = __builtin_amdgcn_mfma_f32_32x32x16_bf16(
                        af[mt], bf[nt], acc[mt][nt], 0, 0, 0);
        }
    };

    // prologue: fill buffer 0 for kt=0
    stage(ivA, Bp, smem + SA0_, smem + SB0_);
    __syncthreads();                            // drains vmcnt(0)
    for (int kt = 0; kt < 32; kt += 2) {
        stage(ivA + (kt + 1) * 64, Bp + (kt + 1) * 64, smem + SA1_, smem + SB1_);
        compute(smem + SA0_, smem + SB0_);
        __syncthreads();
        if (kt + 2 < 32)
            stage(ivA + (kt + 2) * 64, Bp + (kt + 2) * 64, smem + SA0_, smem + SB0_);
        compute(smem + SA1_, smem + SB1_);
        __syncthreads();
    }

    // Epilogue: relu(acc + bias) * xa_w, reduce over n.
    // C/D 32x32: col(n) = lane&31, row(m) = (reg&3) + 8*(reg>>2) + 4*(lane>>5)
    float bias[2], xw[2];
    #pragma unroll
    for (int nt = 0; nt < 2; ++nt) {
        int ng = n0 + wn * 64 + nt * 32 + l31;
        bias[nt] = (ng < DATT_) ? lds1(bcv, ng, f) : 0.f;
        xw[nt]   = (ng < DATT_) ? xa_w[(size_t)b * DATTP_ + ng] : 0.f;
    }
    #pragma unroll
    for (int mt = 0; mt < 4; ++mt) {
        float v[16];
        #pragma unroll
        for (int r = 0; r < 16; ++r) {
            float v0 = fmaxf(acc[mt][0][r] + bias[0], 0.f) * xw[0];
            float v1 = fmaxf(acc[mt][1][r] + bias[1], 0.f) * xw[1];
            v[r] = v0 + v1;
        }
        #pragma unroll
        for (int off = 1; off <= 16; off <<= 1)
            #pragma unroll
            for (int r = 0; r < 16; ++r)
                v[r] += __shfl_xor(v[r], off, 64);
        if (l31 == 0) {
            #pragma unroll
            for (int r = 0; r < 16; ++r) {
                int row = wm * 128 + mt * 32 + (r & 3) + 8 * (r >> 2) + 4 * hi;
                atomicAdd(&llog[row], v[r]);
            }
        }
    }
    __syncthreads();
    if (t < S_)
        atomicAdd(&logits[(size_t)b * 256 + t], llog[t]);
}

// ---------------------------------------------------------------------------
// Kernel 2 fallback (workspace too small): original fused conv-GEMM.
// ---------------------------------------------------------------------------
#define BM_  112
#define BN_  128
#define LDA_ 40
#define LDB_ 40

__global__ __launch_bounds__(256) void k2_gemm(
    const void* __restrict__ iv, const void* __restrict__ Wc,
    const void* __restrict__ bcv, const float* __restrict__ xa_w,
    float* __restrict__ logits, const int* __restrict__ flags)
{
    const int f = flags[0];
    __shared__ ushort_t Al[BM_ * LDA_];
    __shared__ ushort_t Bl[BN_ * LDB_];
    __shared__ float llog[BM_];

    int t = threadIdx.x;
    int bid = blockIdx.x;
    int b   = bid / 20;
    int rem = bid % 20;
    int mb = rem / 10, nb = rem % 10;
    int s0 = mb * BM_, n0 = nb * BN_;
    int rows_valid = min(BM_, S_ - s0);
    int cpc = (rows_valid + 7) >> 3;
    int totA = 32 * cpc;

    if (t < BM_) llog[t] = 0.f;
    for (int idx = t; idx < (BM_ - rows_valid) * LDA_; idx += 256)
        Al[rows_valid * LDA_ + idx] = 0;

    size_t ivbase = (size_t)b * DV_ * S_;

    int wave = t >> 6, lane = t & 63;
    int lquad = lane >> 4, l15 = lane & 15;
    int nbase = wave * 32;

    floatx4 acc[7][2];
    #pragma unroll
    for (int mt = 0; mt < 7; ++mt) {
        acc[mt][0] = floatx4{0.f, 0.f, 0.f, 0.f};
        acc[mt][1] = floatx4{0.f, 0.f, 0.f, 0.f};
    }

    for (int kt = 0; kt < DV_ / 32; ++kt) {
        int k0 = kt * 32;
        __syncthreads();
        for (int idx = t; idx < totA; idx += 256) {
            int c = idx & 31, j = idx >> 5;
            int sr = min(8 * j, rows_valid - 8);
            F8 u = ld8(iv, ivbase + (size_t)(k0 + c) * S_ + s0 + sr, f);
            #pragma unroll
            for (int i = 0; i < 8; ++i)
                Al[(sr + i) * LDA_ + c] = f2bf(u.v[i]);
        }
        for (int idx = t; idx < 512; idx += 256) {
            int nl = idx >> 2, kc = idx & 3;
            int ng = n0 + nl;
            if (ng < DATT_) {
                F8 u = ld8(Wc, (size_t)ng * DV_ + k0 + kc * 8, f);
                #pragma unroll
                for (int i = 0; i < 8; ++i)
                    Bl[nl * LDB_ + kc * 8 + i] = f2bf(u.v[i]);
            } else {
                #pragma unroll
                for (int i = 0; i < 8; ++i)
                    Bl[nl * LDB_ + kc * 8 + i] = 0;
            }
        }
        __syncthreads();
        short8 bf0 = *(const short8*)&Bl[(nbase + l15) * LDB_ + lquad * 8];
        short8 bf1 = *(const short8*)&Bl[(nbase + 16 + l15) * LDB_ + lquad * 8];
        #pragma unroll
        for (int mt = 0; mt < 7; ++mt) {
            short8 af = *(const short8*)&Al[(mt * 16 + l15) * LDA_ + lquad * 8];
            acc[mt][0] = __builtin_amdgcn_mfma_f32_16x16x32_bf16(af, bf0, acc[mt][0], 0, 0, 0);
            acc[mt][1] = __builtin_amdgcn_mfma_f32_16x16x32_bf16(af, bf1, acc[mt][1], 0, 0, 0);
        }
    }

    float bias[2], xw[2];
    #pragma unroll
    for (int bt = 0; bt < 2; ++bt) {
        int ng = n0 + nbase + bt * 16 + l15;
        bias[bt] = (ng < DATT_) ? lds1(bcv, ng, f) : 0.f;
        xw[bt]   = (ng < DATT_) ? xa_w[(size_t)b * DATTP_ + ng] : 0.f;
    }
    float plog[7][4];
    #pragma unroll
    for (int mt = 0; mt < 7; ++mt)
        #pragma unroll
        for (int r = 0; r < 4; ++r) {
            float v0 = fmaxf(acc[mt][0][r] + bias[0], 0.f) * xw[0];
            float v1 = fmaxf(acc[mt][1][r] + bias[1], 0.f) * xw[1];
            plog[mt][r] = v0 + v1;
        }
    #pragma unroll
    for (int off = 1; off <= 8; off <<= 1)
        #pragma unroll
        for (int mt = 0; mt < 7; ++mt)
            #pragma unroll
            for (int r = 0; r < 4; ++r)
                plog[mt][r] += __shfl_xor(plog[mt][r], off, 64);
    if (l15 == 0) {
        #pragma unroll
        for (int mt = 0; mt < 7; ++mt)
            #pragma unroll
            for (int r = 0; r < 4; ++r)
                atomicAdd(&llog[mt * 16 + lquad * 4 + r], plog[mt][r]);
    }
    __syncthreads();
    if (t < rows_valid)
        atomicAdd(&logits[(size_t)b * 256 + s0 + t], llog[t]);
}

// ---------------------------------------------------------------------------
// Kernel 3a: softmax over s (196) per b, IN PLACE.
// ---------------------------------------------------------------------------
__global__ __launch_bounds__(64) void k3a_softmax(float* __restrict__ logits)
{
    int b = blockIdx.x, lane = threadIdx.x;
    float v[4]; float mx = -1e30f;
    #pragma unroll
    for (int i = 0; i < 4; ++i) {
        int s = lane + 64 * i;
        v[i] = (s < S_) ? logits[(size_t)b * 256 + s] : -1e30f;
        union { float f; unsigned u; } cv; cv.f = v[i];
        if ((cv.u & 0x7f800000u) == 0x7f800000u) v[i] = -1e30f;
        mx = fmaxf(mx, v[i]);
    }
    #pragma unroll
    for (int off = 1; off < 64; off <<= 1)
        mx = fmaxf(mx, __shfl_xor(mx, off, 64));
    float e[4]; float sum = 0.f;
    #pragma unroll
    for (int i = 0; i < 4; ++i) {
        int s = lane + 64 * i;
        e[i] = (s < S_) ? __expf(v[i] - mx) : 0.f;
        sum += e[i];
    }
    #pragma unroll
    for (int off = 1; off < 64; off <<= 1)
        sum += __shfl_xor(sum, off, 64);
    float inv = 1.f / sum;
    #pragma unroll
    for (int i = 0; i < 4; ++i) {
        int s = lane + 64 * i;
        if (s < S_) logits[(size_t)b * 256 + s] = e[i] * inv;
    }
}

// ---------------------------------------------------------------------------
// Kernel 3b: x_v_att[b,d] = sum_s attn[b,s] * input_v[b,d,s]
// Wave-per-row: 49 lanes x 16B = one contiguous 784B row read per wave-instr.
// grid 2048 = b(256) x dchunk(8), block 256 (4 waves, 64 rows each)
// ---------------------------------------------------------------------------
__global__ __launch_bounds__(256) void k3b_wsum(
    const void* __restrict__ iv, const float* __restrict__ attn,
    float* __restrict__ xvatt, const int* __restrict__ flags)
{
    const int f = flags[0];
    __shared__ float at[200];
    int t = threadIdx.x;
    int b = blockIdx.x >> 3, dc = blockIdx.x & 7;
    if (t < S_) at[t] = attn[(size_t)b * 256 + t];
    __syncthreads();
    int wave = t >> 6, lane = t & 63;
    int s = 4 * lane;                       // lanes 0..48 active (4*49 = 196)
    float a0 = 0.f, a1 = 0.f, a2 = 0.f, a3 = 0.f;
    if (s < S_) { a0 = at[s]; a1 = at[s+1]; a2 = at[s+2]; a3 = at[s+3]; }
    int dbase = dc * 256 + wave * 64;
    size_t rowb = ((size_t)b * DV_ + dbase) * S_;
    #pragma unroll 4
    for (int rr = 0; rr < 64; ++rr) {
        float p = 0.f;
        if (s < S_) {
            F4 u = ld4(iv, rowb + (size_t)rr * S_ + s, f);
            p = u.v[0]*a0 + u.v[1]*a1 + u.v[2]*a2 + u.v[3]*a3;
        }
        #pragma unroll
        for (int off = 1; off < 64; off <<= 1)
            p += __shfl_xor(p, off, 64);
        if (lane == 0) xvatt[(size_t)b * DV_ + dbase + rr] = p;
    }
}

// ---------------------------------------------------------------------------
// Kernel 3c: v_feat = x_v_att @ W_img^T + b_img -> out[:, :1024]
// grid 512 = ochunk(16, 64 rows) x bchunk(32, 8 b) -> 2 blocks/CU
// ---------------------------------------------------------------------------
__global__ __launch_bounds__(256) void k3c_vfeat(
    const float* __restrict__ xvatt, const void* __restrict__ Wimg,
    const void* __restrict__ bimg, void* __restrict__ out,
    const int* __restrict__ flags)
{
    const int f = flags[0];
    __shared__ float xv[DV_];
    int t = threadIdx.x;
    int oc = blockIdx.x >> 5, bc2 = blockIdx.x & 31;
    int o0 = oc * 64, b0 = bc2 * 8;
    int wave = t >> 6, lane = t & 63;
    for (int bb = 0; bb < 8; ++bb) {
        int b = b0 + bb;
        __syncthreads();
        {
            const float4* src = (const float4*)(xvatt + (size_t)b * DV_);
            float4* dst = (float4*)xv;
            dst[t] = src[t];
            dst[t + 256] = src[t + 256];
        }
        __syncthreads();
        for (int j = 0; j < 16; ++j) {
            int o = o0 + wave * 16 + j;
            size_t wrow = (size_t)o * DV_;
            float p = 0.f;
            #pragma unroll
            for (int i = 0; i < 4; ++i) {
                int c = 8 * lane + 512 * i;
                F8 u = ld8(Wimg, wrow + c, f);
                p += u.v[0]*xv[c+0] + u.v[1]*xv[c+1] + u.v[2]*xv[c+2] + u.v[3]*xv[c+3];
                p += u.v[4]*xv[c+4] + u.v[5]*xv[c+5] + u.v[6]*xv[c+6] + u.v[7]*xv[c+7];
            }
            #pragma unroll
            for (int off = 1; off < 64; off <<= 1)
                p += __shfl_xor(p, off, 64);
            if (lane == 0)
                stout(out, (size_t)b * 2048 + o, p + lds1(bimg, o, f), f);
        }
    }
}

// ---------------------------------------------------------------------------
extern "C" void kernel_launch(void* const* d_in, const int* in_sizes, int n_in,
                              void* d_out, int out_size, void* d_ws, size_t ws_size,
                              hipStream_t stream)
{
    const void* iv   = d_in[0];   // input_v  [256,2048,196]
    const void* emb  = d_in[1];   // emb      [3000,620]
    const void* Wc   = d_in[2];   // W_conv_v [1200,2048]
    const void* bcv  = d_in[3];   // b_conv_v [1200]
    const void* Wla  = d_in[4];   // W_lin_a  [1200,620]
    const void* bla  = d_in[5];   // b_lin_a  [1200]
    const void* watt = d_in[6];   // w_att    [1200]
    // d_in[7] = b_att: softmax shift-invariant, unused
    const void* Wimg = d_in[8];   // W_img    [1024,2048]
    const void* bimg = d_in[9];   // b_img    [1024]
    const void* Wans = d_in[10];  // W_ans    [1024,620]
    const void* bans = d_in[11];  // b_ans    [1024]
    const int*  ia   = (const int*)d_in[12];  // input_a [256] int32

    char* ws = (char*)d_ws;
    float* xa_w   = (float*)(ws);                      // 1,310,720 B
    float* logits = (float*)(ws + 1310720);            //   262,144 B
    float* xvatt  = (float*)(ws + 1572864);            // 2,097,152 B
    int*   flags  = (int*)(ws + 3670016);              //     4,096 B
    ushort_t* Wcb = (ushort_t*)(ws + 3674112);         // 5,242,880 B
    ushort_t* ivb = (ushort_t*)(ws + 8916992);         // 234,881,024 B
    const size_t WS_NEED = 8916992ull + (size_t)B_ * IVB_SSTR * DV_ * 2;

    hipMemsetAsync(logits, 0, 256 * 256 * 4, stream);
    k0_detect<<<1, 64, 0, stream>>>(emb, flags);
    k1_xa<<<512, 256, 0, stream>>>(emb, ia, Wla, bla, watt, Wans, bans, xa_w, d_out, flags);
    if (ws_size >= WS_NEED) {
        kp_w<<<1280, 256, 0, stream>>>(Wc, Wcb, flags);
        kp_iv<<<32768, 256, 0, stream>>>(iv, ivb, flags);
        k2_gemm_v3<<<1280, 512, 0, stream>>>(ivb, Wcb, bcv, xa_w, logits, flags);
    } else {
        k2_gemm<<<5120, 256, 0, stream>>>(iv, Wc, bcv, xa_w, logits, flags);
    }
    k3a_softmax<<<256, 64, 0, stream>>>(logits);
    k3b_wsum<<<2048, 256, 0, stream>>>(iv, logits, xvatt, flags);
    k3c_vfeat<<<512, 256, 0, stream>>>(xvatt, Wimg, bimg, d_out, flags);
}